// Round 1
// baseline (1750.559 us; speedup 1.0000x reference)
//
#include <hip/hip_runtime.h>
#include <math.h>

#define B_DIM 4
#define S_DIM 4096
#define E_DIM 1024
#define A_DIM 64
#define M_TOT (B_DIM * S_DIM) /* 16384 */

// ---------------------------------------------------------------------------
// Kernel 1: QKV projection.  X:[16384,1024] fp32, W:[64,1024] fp32 (row-major,
// y = x @ W^T).  Classic 64x64 LDS-tiled GEMM, BK=32, 4x4 register tile.
// blockIdx.y selects which of the three projections.
// ---------------------------------------------------------------------------
__global__ __launch_bounds__(256) void qkv_proj_kernel(
    const float* __restrict__ X,
    const float* __restrict__ Wq,
    const float* __restrict__ Wk,
    const float* __restrict__ Wv,
    float* __restrict__ Qb,
    float* __restrict__ Kb,
    float* __restrict__ Vb)
{
    const float* W;
    float* O;
    if (blockIdx.y == 0)      { W = Wq; O = Qb; }
    else if (blockIdx.y == 1) { W = Wk; O = Kb; }
    else                      { W = Wv; O = Vb; }

    const int r0 = blockIdx.x * 64;

    // +4 pad keeps float4 alignment (stride 36 floats = 144 B) and breaks
    // power-of-2 bank strides.
    __shared__ __align__(16) float Xs[64][36];
    __shared__ __align__(16) float Ws[64][36];

    const int t  = threadIdx.x;
    const int tx = t & 15;   // 16 col groups of 4
    const int ty = t >> 4;   // 16 row groups of 4

    float acc[4][4];
#pragma unroll
    for (int i = 0; i < 4; ++i)
#pragma unroll
        for (int j = 0; j < 4; ++j) acc[i][j] = 0.0f;

    const int f   = (t & 7) * 4; // float offset within the 32-wide K chunk
    const int row = t >> 3;      // 0..31

    for (int k0 = 0; k0 < E_DIM; k0 += 32) {
        float4 xa = *(const float4*)(X + (size_t)(r0 + row)      * E_DIM + k0 + f);
        float4 xb = *(const float4*)(X + (size_t)(r0 + row + 32) * E_DIM + k0 + f);
        float4 wa = *(const float4*)(W + (size_t)(row)      * E_DIM + k0 + f);
        float4 wb = *(const float4*)(W + (size_t)(row + 32) * E_DIM + k0 + f);
        __syncthreads(); // previous iteration's compute done before overwrite
        *(float4*)&Xs[row][f]      = xa;
        *(float4*)&Xs[row + 32][f] = xb;
        *(float4*)&Ws[row][f]      = wa;
        *(float4*)&Ws[row + 32][f] = wb;
        __syncthreads();
#pragma unroll
        for (int kk = 0; kk < 32; kk += 4) {
            float4 xr[4], wc[4];
#pragma unroll
            for (int i = 0; i < 4; ++i) xr[i] = *(float4*)&Xs[ty * 4 + i][kk];
#pragma unroll
            for (int j = 0; j < 4; ++j) wc[j] = *(float4*)&Ws[tx * 4 + j][kk];
#pragma unroll
            for (int i = 0; i < 4; ++i)
#pragma unroll
                for (int j = 0; j < 4; ++j) {
                    acc[i][j] = fmaf(xr[i].x, wc[j].x, acc[i][j]);
                    acc[i][j] = fmaf(xr[i].y, wc[j].y, acc[i][j]);
                    acc[i][j] = fmaf(xr[i].z, wc[j].z, acc[i][j]);
                    acc[i][j] = fmaf(xr[i].w, wc[j].w, acc[i][j]);
                }
        }
    }

#pragma unroll
    for (int i = 0; i < 4; ++i) {
        float4 v = make_float4(acc[i][0], acc[i][1], acc[i][2], acc[i][3]);
        *(float4*)(O + (size_t)(r0 + ty * 4 + i) * A_DIM + tx * 4) = v;
    }
}

// ---------------------------------------------------------------------------
// Kernel 2: causal flash attention, fp32.
// Block = 256 threads = 4 waves; one 64-query tile per block (batch b, tile qt).
// Each lane owns one query row: Q row (64 f32) and O accumulator (64 f32) in
// VGPRs, online-softmax scalars m,l per lane.  The 4 waves split the key tiles
// 4-way (kt = w, w+4, ...), partial (m,l,O) combined through LDS at the end.
// K/V rows are read at wave-uniform addresses -> scalar loads, broadcast free.
// ---------------------------------------------------------------------------
__global__ __launch_bounds__(256, 1) void attn_kernel(
    const float* __restrict__ Qb,
    const float* __restrict__ Kb,
    const float* __restrict__ Vb,
    float* __restrict__ out)
{
    const int b    = blockIdx.y;
    const int qt   = (int)(gridDim.x - 1) - (int)blockIdx.x; // big tiles first
    const int w    = threadIdx.x >> 6;
    const int lane = threadIdx.x & 63;

    __shared__ __align__(16) float red_m[4][64];
    __shared__ __align__(16) float red_l[4][64];
    __shared__ __align__(16) float red_o[4][64][68]; // +4 pad per row

    const int q = qt * 64 + lane;
    const float* qptr = Qb + (size_t)(b * S_DIM + q) * A_DIM;

    float qreg[64];
#pragma unroll
    for (int e4 = 0; e4 < 16; ++e4) {
        float4 v = *(const float4*)(qptr + e4 * 4);
        qreg[e4 * 4 + 0] = v.x; qreg[e4 * 4 + 1] = v.y;
        qreg[e4 * 4 + 2] = v.z; qreg[e4 * 4 + 3] = v.w;
    }

    float m = -INFINITY, lsum = 0.0f;
    float o[64];
#pragma unroll
    for (int e = 0; e < 64; ++e) o[e] = 0.0f;

    for (int kt = w; kt <= qt; kt += 4) {
        const float* Kt = Kb + (size_t)(b * S_DIM + kt * 64) * A_DIM;
        const float* Vt = Vb + (size_t)(b * S_DIM + kt * 64) * A_DIM;
        const bool diag = (kt == qt);

        for (int jj = 0; jj < 64; jj += 16) {
            float sv[16];
#pragma unroll
            for (int j = 0; j < 16; ++j) {
                const float* kr = Kt + (size_t)(jj + j) * A_DIM;
                float s0 = 0.f, s1 = 0.f, s2 = 0.f, s3 = 0.f;
#pragma unroll
                for (int e = 0; e < 64; e += 4) {
                    s0 = fmaf(qreg[e + 0], kr[e + 0], s0);
                    s1 = fmaf(qreg[e + 1], kr[e + 1], s1);
                    s2 = fmaf(qreg[e + 2], kr[e + 2], s2);
                    s3 = fmaf(qreg[e + 3], kr[e + 3], s3);
                }
                float s = ((s0 + s1) + (s2 + s3)) * 0.125f; // 1/sqrt(64)
                if (diag && (jj + j) > lane) s = -INFINITY;
                sv[j] = s;
            }
            float tmax = sv[0];
#pragma unroll
            for (int j = 1; j < 16; ++j) tmax = fmaxf(tmax, sv[j]);
            const float mnew  = fmaxf(m, tmax);
            const float alpha = __expf(m - mnew); // m=-inf first time -> 0
            lsum *= alpha;
#pragma unroll
            for (int e = 0; e < 64; ++e) o[e] *= alpha;
#pragma unroll
            for (int j = 0; j < 16; ++j) {
                const float p = __expf(sv[j] - mnew);
                lsum += p;
                const float* vr = Vt + (size_t)(jj + j) * A_DIM;
#pragma unroll
                for (int e = 0; e < 64; ++e) o[e] = fmaf(p, vr[e], o[e]);
            }
            m = mnew;
        }
    }

    // ---- combine the 4 key-split partials through LDS ----
    red_m[w][lane] = m;
    red_l[w][lane] = lsum;
#pragma unroll
    for (int e4 = 0; e4 < 16; ++e4) {
        float4 v = make_float4(o[e4 * 4 + 0], o[e4 * 4 + 1],
                               o[e4 * 4 + 2], o[e4 * 4 + 3]);
        *(float4*)&red_o[w][lane][e4 * 4] = v;
    }
    __syncthreads();

    if (threadIdx.x < 64) {
        const int qq = threadIdx.x;
        const float m0 = red_m[0][qq], m1 = red_m[1][qq];
        const float m2 = red_m[2][qq], m3 = red_m[3][qq];
        const float ms = fmaxf(fmaxf(m0, m1), fmaxf(m2, m3)); // finite (wave0)
        const float c0 = __expf(m0 - ms), c1 = __expf(m1 - ms);
        const float c2 = __expf(m2 - ms), c3 = __expf(m3 - ms);
        const float denom = c0 * red_l[0][qq] + c1 * red_l[1][qq]
                          + c2 * red_l[2][qq] + c3 * red_l[3][qq];
        const float inv = 1.0f / denom;
        red_m[0][qq] = c0 * inv; red_m[1][qq] = c1 * inv;
        red_m[2][qq] = c2 * inv; red_m[3][qq] = c3 * inv;
    }
    __syncthreads();

    for (int u = threadIdx.x; u < 1024; u += 256) {
        const int qq = u >> 4;
        const int e4 = (u & 15) * 4;
        const float c0 = red_m[0][qq], c1 = red_m[1][qq];
        const float c2 = red_m[2][qq], c3 = red_m[3][qq];
        const float4 o0 = *(float4*)&red_o[0][qq][e4];
        const float4 o1 = *(float4*)&red_o[1][qq][e4];
        const float4 o2 = *(float4*)&red_o[2][qq][e4];
        const float4 o3 = *(float4*)&red_o[3][qq][e4];
        float4 r;
        r.x = c0 * o0.x + c1 * o1.x + c2 * o2.x + c3 * o3.x;
        r.y = c0 * o0.y + c1 * o1.y + c2 * o2.y + c3 * o3.y;
        r.z = c0 * o0.z + c1 * o1.z + c2 * o2.z + c3 * o3.z;
        r.w = c0 * o0.w + c1 * o1.w + c2 * o2.w + c3 * o3.w;
        *(float4*)(out + (size_t)(b * S_DIM + qt * 64 + qq) * A_DIM + e4) = r;
    }
}

// ---------------------------------------------------------------------------
extern "C" void kernel_launch(void* const* d_in, const int* in_sizes, int n_in,
                              void* d_out, int out_size, void* d_ws, size_t ws_size,
                              hipStream_t stream)
{
    const float* X  = (const float*)d_in[0]; // embedded
    const float* Wk = (const float*)d_in[1]; // W_K
    const float* Wq = (const float*)d_in[2]; // W_Q
    const float* Wv = (const float*)d_in[3]; // W_V
    float* out = (float*)d_out;

    float* Qb = (float*)d_ws;                       // [16384, 64]
    float* Kb = Qb + (size_t)M_TOT * A_DIM;         // [16384, 64]
    float* Vb = Kb + (size_t)M_TOT * A_DIM;         // [16384, 64]

    dim3 g1(M_TOT / 64, 3), b1(256);
    qkv_proj_kernel<<<g1, b1, 0, stream>>>(X, Wq, Wk, Wv, Qb, Kb, Vb);

    dim3 g2(S_DIM / 64, B_DIM), b2(256);
    attn_kernel<<<g2, b2, 0, stream>>>(Qb, Kb, Vb, out);
}

// Round 2
// 200.965 us; speedup vs baseline: 8.7108x; 8.7108x over previous
//
#include <hip/hip_runtime.h>
#include <math.h>

#define B_DIM 4
#define S_DIM 4096
#define E_DIM 1024
#define A_DIM 64
#define M_TOT (B_DIM * S_DIM) /* 16384 */

typedef __bf16 v8bf __attribute__((ext_vector_type(8)));
typedef __bf16 v4bf __attribute__((ext_vector_type(4)));
typedef float  v4f  __attribute__((ext_vector_type(4)));

__device__ __forceinline__ v4f mfma16(v8bf a, v8bf b, v4f c) {
    return __builtin_amdgcn_mfma_f32_16x16x32_bf16(a, b, c, 0, 0, 0);
}

// ---------------------------------------------------------------------------
// QKV projection, MFMA bf16.  One wave (64 thr) per block; each wave computes
// a 64-row x 64-col output tile over K=1024.  grid=(256 row-tiles, 3 weights).
//   A-frag: X[m=lane&15][k=quad*8+j]  (fp32 load -> bf16 cvt)
//   B-frag: W[n=lane&15][k=quad*8+j]
//   C-layout: row = quad*4+reg (+16*mi), col = lane&15 (+16*ni)
// wgt 0 -> K (natural [s][a] bf16), wgt 1 -> Q (x 1/8, natural), wgt 2 -> V
// stored TRANSPOSED as Vt[a][s] bf16 (via LDS transpose) for PV A-frags.
// ---------------------------------------------------------------------------
__global__ __launch_bounds__(64, 1) void qkv_proj_mfma(
    const float* __restrict__ X,
    const float* __restrict__ Wk,
    const float* __restrict__ Wq,
    const float* __restrict__ Wv,
    __bf16* __restrict__ Kb,
    __bf16* __restrict__ Qb,
    __bf16* __restrict__ Vt)
{
    const int wgt = blockIdx.y;
    const float* W = (wgt == 0) ? Wk : (wgt == 1) ? Wq : Wv;
    const int r0   = blockIdx.x * 64;
    const int lane = threadIdx.x;
    const int L    = lane & 15;
    const int quad = lane >> 4;

    __shared__ float Tt[64][65]; // transpose staging (V only); pad -> no conflicts

    v4f acc[4][4];
#pragma unroll
    for (int i = 0; i < 4; ++i)
#pragma unroll
        for (int j = 0; j < 4; ++j) acc[i][j] = (v4f){0.f, 0.f, 0.f, 0.f};

    const int kb = quad * 8;
    for (int kc = 0; kc < 32; ++kc) {
        const int k0 = kc * 32 + kb;
        v8bf af[4], bfr[4];
#pragma unroll
        for (int mi = 0; mi < 4; ++mi) {
            const float* p = X + (size_t)(r0 + mi * 16 + L) * E_DIM + k0;
            float4 a = *(const float4*)p;
            float4 b = *(const float4*)(p + 4);
            v8bf f;
            f[0] = (__bf16)a.x; f[1] = (__bf16)a.y; f[2] = (__bf16)a.z; f[3] = (__bf16)a.w;
            f[4] = (__bf16)b.x; f[5] = (__bf16)b.y; f[6] = (__bf16)b.z; f[7] = (__bf16)b.w;
            af[mi] = f;
        }
#pragma unroll
        for (int ni = 0; ni < 4; ++ni) {
            const float* p = W + (size_t)(ni * 16 + L) * E_DIM + k0;
            float4 a = *(const float4*)p;
            float4 b = *(const float4*)(p + 4);
            v8bf f;
            f[0] = (__bf16)a.x; f[1] = (__bf16)a.y; f[2] = (__bf16)a.z; f[3] = (__bf16)a.w;
            f[4] = (__bf16)b.x; f[5] = (__bf16)b.y; f[6] = (__bf16)b.z; f[7] = (__bf16)b.w;
            bfr[ni] = f;
        }
#pragma unroll
        for (int mi = 0; mi < 4; ++mi)
#pragma unroll
            for (int ni = 0; ni < 4; ++ni)
                acc[mi][ni] = mfma16(af[mi], bfr[ni], acc[mi][ni]);
    }

    if (wgt < 2) {
        __bf16* O = (wgt == 0) ? Kb : Qb;
        const float scale = (wgt == 1) ? 0.125f : 1.0f; // fold 1/sqrt(64) into Q
#pragma unroll
        for (int mi = 0; mi < 4; ++mi)
#pragma unroll
            for (int ni = 0; ni < 4; ++ni)
#pragma unroll
                for (int r = 0; r < 4; ++r)
                    O[(size_t)(r0 + mi * 16 + quad * 4 + r) * A_DIM + ni * 16 + L] =
                        (__bf16)(acc[mi][ni][r] * scale);
    } else {
        // V: transpose through LDS, emit Vt[a][s] rows (16B-vectorized).
#pragma unroll
        for (int mi = 0; mi < 4; ++mi)
#pragma unroll
            for (int ni = 0; ni < 4; ++ni)
#pragma unroll
                for (int r = 0; r < 4; ++r)
                    Tt[mi * 16 + quad * 4 + r][ni * 16 + L] = acc[mi][ni][r];
        __syncthreads();
        const int batch = r0 >> 12;       // r0 / 4096
        const int s0    = r0 & 4095;
        __bf16* vrow = Vt + (size_t)(batch * 64 + lane) * S_DIM + s0;
#pragma unroll
        for (int s8 = 0; s8 < 64; s8 += 8) {
            v8bf pk;
#pragma unroll
            for (int j = 0; j < 8; ++j) pk[j] = (__bf16)Tt[s8 + j][lane];
            *(v8bf*)(vrow + s8) = pk;
        }
    }
}

// ---------------------------------------------------------------------------
// Causal flash attention, MFMA bf16.
// Block = 4 waves, one 64-query tile (b, qt).  Wave w handles kt = w, w+4, ...
// Computes S^T = K.Q^T (so softmax reduces along C-layout rows via shfl),
// P^T -> LDS (transposed store: packed b64 writes, b128 frag reads),
// O^T = V^T.P^T with V^T A-frags straight from global.
// 4-way wave partials (m,l,O^T) combined through LDS at the end.
// ---------------------------------------------------------------------------
__global__ __launch_bounds__(256, 1) void attn_mfma(
    const __bf16* __restrict__ Qb,
    const __bf16* __restrict__ Kb,
    const __bf16* __restrict__ Vt,
    float* __restrict__ out)
{
    const int b    = blockIdx.y;
    const int qt   = blockIdx.x;
    const int w    = threadIdx.x >> 6;
    const int lane = threadIdx.x & 63;
    const int L    = lane & 15;
    const int quad = lane >> 4;

    __shared__ __bf16 Pt[4][64][72];       // per-wave P^T as [q][k'], pad 8
    __shared__ float  red_m[4][64];
    __shared__ float  red_l[4][64];
    __shared__ float  red_o[4][64][65];    // [w][a][q], pad 1

    // Q B-frags, resident: Q[q = ni*16+L][a = ka*32 + quad*8 + j]
    v8bf qf[4][2];
#pragma unroll
    for (int ni = 0; ni < 4; ++ni)
#pragma unroll
        for (int ka = 0; ka < 2; ++ka)
            qf[ni][ka] = *(const v8bf*)(Qb +
                (size_t)(b * S_DIM + qt * 64 + ni * 16 + L) * A_DIM + ka * 32 + quad * 8);

    v4f acc_o[4][4];
#pragma unroll
    for (int i = 0; i < 4; ++i)
#pragma unroll
        for (int j = 0; j < 4; ++j) acc_o[i][j] = (v4f){0.f, 0.f, 0.f, 0.f};
    float mrun[4] = {-INFINITY, -INFINITY, -INFINITY, -INFINITY};
    float lrun[4] = {0.f, 0.f, 0.f, 0.f};

    const int maxtrips = qt / 4 + 1;
    for (int t = 0; t < maxtrips; ++t) {
        const int kt = w + 4 * t;
        const bool active = (kt <= qt);

        if (active) {
            // K A-frags: K[k' = mi*16+L][a = ka*32+quad*8+j]
            v8bf kf[4][2];
#pragma unroll
            for (int mi = 0; mi < 4; ++mi)
#pragma unroll
                for (int ka = 0; ka < 2; ++ka)
                    kf[mi][ka] = *(const v8bf*)(Kb +
                        (size_t)(b * S_DIM + kt * 64 + mi * 16 + L) * A_DIM + ka * 32 + quad * 8);

            // S^T tiles: rows k' (mi), cols q (ni)
            v4f s[4][4];
#pragma unroll
            for (int i = 0; i < 4; ++i)
#pragma unroll
                for (int j = 0; j < 4; ++j) s[i][j] = (v4f){0.f, 0.f, 0.f, 0.f};
#pragma unroll
            for (int mi = 0; mi < 4; ++mi)
#pragma unroll
                for (int ni = 0; ni < 4; ++ni)
#pragma unroll
                    for (int ka = 0; ka < 2; ++ka)
                        s[mi][ni] = mfma16(kf[mi][ka], qf[ni][ka], s[mi][ni]);

            if (kt == qt) { // diagonal tile: mask k'_loc > q_loc
#pragma unroll
                for (int mi = 0; mi < 4; ++mi)
#pragma unroll
                    for (int ni = 0; ni < 4; ++ni)
#pragma unroll
                        for (int r = 0; r < 4; ++r)
                            if (mi * 16 + quad * 4 + r > ni * 16 + L)
                                s[mi][ni][r] = -INFINITY;
            }

            // online softmax per q-column (ni tiles); reduce over mi,r + quads
            float alpha[4];
#pragma unroll
            for (int ni = 0; ni < 4; ++ni) {
                float tm = -INFINITY;
#pragma unroll
                for (int mi = 0; mi < 4; ++mi)
#pragma unroll
                    for (int r = 0; r < 4; ++r) tm = fmaxf(tm, s[mi][ni][r]);
                tm = fmaxf(tm, __shfl_xor(tm, 16, 64));
                tm = fmaxf(tm, __shfl_xor(tm, 32, 64));
                const float mn = fmaxf(mrun[ni], tm);
                alpha[ni] = __expf(mrun[ni] - mn); // -inf first time -> 0
                mrun[ni]  = mn;
                float rs = 0.f;
#pragma unroll
                for (int mi = 0; mi < 4; ++mi)
#pragma unroll
                    for (int r = 0; r < 4; ++r) {
                        const float p = __expf(s[mi][ni][r] - mn);
                        s[mi][ni][r] = p;
                        rs += p;
                    }
                rs += __shfl_xor(rs, 16, 64);
                rs += __shfl_xor(rs, 32, 64);
                lrun[ni] = lrun[ni] * alpha[ni] + rs;
            }

            // write P^T to LDS as [q][k']: 4 consecutive k' -> packed 8B store
#pragma unroll
            for (int mi = 0; mi < 4; ++mi)
#pragma unroll
                for (int ni = 0; ni < 4; ++ni) {
                    v4bf p4;
                    p4[0] = (__bf16)s[mi][ni][0];
                    p4[1] = (__bf16)s[mi][ni][1];
                    p4[2] = (__bf16)s[mi][ni][2];
                    p4[3] = (__bf16)s[mi][ni][3];
                    *(v4bf*)&Pt[w][ni * 16 + L][mi * 16 + quad * 4] = p4;
                }

            // rescale O^T columns by alpha[q-tile]
#pragma unroll
            for (int ma = 0; ma < 4; ++ma)
#pragma unroll
                for (int ni = 0; ni < 4; ++ni)
#pragma unroll
                    for (int r = 0; r < 4; ++r) acc_o[ma][ni][r] *= alpha[ni];
        }
        __syncthreads(); // P^T visible wave-internally (uniform: all waves hit)

        if (active) {
            // V^T A-frags from global; P^T B-frags from LDS
            v8bf vf[4][2], pf[4][2];
#pragma unroll
            for (int ma = 0; ma < 4; ++ma)
#pragma unroll
                for (int ki = 0; ki < 2; ++ki)
                    vf[ma][ki] = *(const v8bf*)(Vt +
                        (size_t)(b * 64 + ma * 16 + L) * S_DIM + kt * 64 + ki * 32 + quad * 8);
#pragma unroll
            for (int ni = 0; ni < 4; ++ni)
#pragma unroll
                for (int ki = 0; ki < 2; ++ki)
                    pf[ni][ki] = *(const v8bf*)&Pt[w][ni * 16 + L][ki * 32 + quad * 8];
#pragma unroll
            for (int ma = 0; ma < 4; ++ma)
#pragma unroll
                for (int ni = 0; ni < 4; ++ni)
#pragma unroll
                    for (int ki = 0; ki < 2; ++ki)
                        acc_o[ma][ni] = mfma16(vf[ma][ki], pf[ni][ki], acc_o[ma][ni]);
        }
        __syncthreads(); // protect P^T against next trip's overwrite
    }

    // ---- cross-wave combine ----
    if (quad == 0) {
#pragma unroll
        for (int ni = 0; ni < 4; ++ni) {
            red_m[w][ni * 16 + L] = mrun[ni];
            red_l[w][ni * 16 + L] = lrun[ni];
        }
    }
#pragma unroll
    for (int ma = 0; ma < 4; ++ma)
#pragma unroll
        for (int ni = 0; ni < 4; ++ni)
#pragma unroll
            for (int r = 0; r < 4; ++r)
                red_o[w][ma * 16 + quad * 4 + r][ni * 16 + L] = acc_o[ma][ni][r];
    __syncthreads();

    if (threadIdx.x < 64) {
        const int q = threadIdx.x;
        const float m0 = red_m[0][q], m1 = red_m[1][q];
        const float m2 = red_m[2][q], m3 = red_m[3][q];
        const float ms = fmaxf(fmaxf(m0, m1), fmaxf(m2, m3)); // finite (diag wave)
        const float c0 = __expf(m0 - ms), c1 = __expf(m1 - ms);
        const float c2 = __expf(m2 - ms), c3 = __expf(m3 - ms);
        const float denom = c0 * red_l[0][q] + c1 * red_l[1][q]
                          + c2 * red_l[2][q] + c3 * red_l[3][q];
        const float inv = 1.0f / denom;
        red_m[0][q] = c0 * inv; red_m[1][q] = c1 * inv;
        red_m[2][q] = c2 * inv; red_m[3][q] = c3 * inv;
    }
    __syncthreads();

    // out[q][a] = sum_w cw[q] * O^T_w[a][q]   (coalesced float4 rows)
    {
        const int q  = threadIdx.x >> 2;
        const int ac = (threadIdx.x & 3) << 4;
        const float c0 = red_m[0][q], c1 = red_m[1][q];
        const float c2 = red_m[2][q], c3 = red_m[3][q];
        float* orow = out + (size_t)(b * S_DIM + qt * 64 + q) * A_DIM;
#pragma unroll
        for (int i4 = 0; i4 < 4; ++i4) {
            float vv[4];
#pragma unroll
            for (int j = 0; j < 4; ++j) {
                const int a = ac + i4 * 4 + j;
                vv[j] = c0 * red_o[0][a][q] + c1 * red_o[1][a][q]
                      + c2 * red_o[2][a][q] + c3 * red_o[3][a][q];
            }
            *(float4*)(orow + ac + i4 * 4) = make_float4(vv[0], vv[1], vv[2], vv[3]);
        }
    }
}

// ---------------------------------------------------------------------------
extern "C" void kernel_launch(void* const* d_in, const int* in_sizes, int n_in,
                              void* d_out, int out_size, void* d_ws, size_t ws_size,
                              hipStream_t stream)
{
    const float* X  = (const float*)d_in[0]; // embedded [4,4096,1024]
    const float* Wk = (const float*)d_in[1]; // W_K [64,1024]
    const float* Wq = (const float*)d_in[2]; // W_Q
    const float* Wv = (const float*)d_in[3]; // W_V
    float* out = (float*)d_out;

    __bf16* Kb = (__bf16*)d_ws;                     // [16384][64] bf16
    __bf16* Qb = Kb + (size_t)M_TOT * A_DIM;        // [16384][64] bf16 (x 1/8)
    __bf16* Vt = Qb + (size_t)M_TOT * A_DIM;        // [4*64][4096] bf16 (V^T)

    dim3 g1(M_TOT / 64, 3), b1(64);
    qkv_proj_mfma<<<g1, b1, 0, stream>>>(X, Wk, Wq, Wv, Kb, Qb, Vt);

    dim3 g2(S_DIM / 64, B_DIM), b2(256);
    attn_mfma<<<g2, b2, 0, stream>>>(Qb, Kb, Vt, out);
}